// Round 11
// baseline (708.419 us; speedup 1.0000x reference)
//
#include <hip/hip_runtime.h>
#include <stdint.h>

typedef int v4i  __attribute__((ext_vector_type(4)));
typedef int v16i __attribute__((ext_vector_type(16)));

#define M_TOK 8192
#define N_OUT 4096
#define K_IN  4096

#define BM 256
#define BN 256
#define BK 64                      // bytes (= i8 elems) per K-tile
#define NT (K_IN / BK)             // 64 K-tiles
#define RING_STRIDE 32768          // A 16 KiB + B 16 KiB per ring slot
#define LDS_BYTES (4 * RING_STRIDE)  // 128 KiB, ring of 4

// sched_group_barrier masks (LLVM SchedGroupMask, verified m137)
#define SGB __builtin_amdgcn_sched_group_barrier
#define SG_MFMA 0x8
#define SG_VMEM 0x20
#define SG_DSRD 0x100

// -------------------------------------------------------------------------
// Pack both int32-carrier tensors into int8 in one dispatch. (~38 us,
// BW-bound: 240 MB @ ~6.3 TB/s)
// -------------------------------------------------------------------------
__device__ __forceinline__ int pack4(int4 a) {
    return (a.x & 255) | ((a.y & 255) << 8) | ((a.z & 255) << 16) | ((a.w & 255) << 24);
}

__global__ __launch_bounds__(256) void pack_both(
    const int4* __restrict__ x, const int4* __restrict__ w,
    int* __restrict__ dA, int* __restrict__ dB, int n4x, int n4w)
{
    int i = blockIdx.x * blockDim.x + threadIdx.x;
    if (i < n4x) {
        dA[i] = pack4(x[i]);
    } else {
        int j = i - n4x;
        if (j < n4w) dB[j] = pack4(w[j]);
    }
}

// -------------------------------------------------------------------------
// i8 GEMM, R11: SQUARE 128x128 WAVE TILE (4 waves of 4x4 frags). Evidence
// chain: six schedule structures (R3 barrier-min, R5 reg pipeline, R6/R7
// 2-block, R8 SGB interleave, R10 split-pipe) all pinned at the serial sum
// MFMA(1171) + LDS(~1536) cyc/K-tile; R9/R10 proved the VMEM path is
// worse and that conflicts = 4.0/ds_read invariant (read floor, not
// fixable). So shrink the LDS term instead of trying to overlap it:
// 128x64 wave tiles read A x4 / B x2 (96 KB/tile, 0.75 reads/MFMA);
// 128x128 wave tiles read A x2 / B x2 (64 KB/tile, 0.5 reads/MFMA).
// LDS demand 1536 -> ~1030 cyc; serial-sum floor 2200 cyc/tile = ~117 us
// gemm WITHOUT requiring pipe overlap. Cost: acc[4][4] = 256 unified regs
// -> 1 wave/SIMD (forfeits wave overlap that measurements say never
// existed). launch_bounds(256,1): reg cap 512 (R6 lesson: (512,4) capped
// at 128 and spilled acc -> 15 GB scratch traffic).
// R8's verified skeleton: ring-4, 1 barrier/tile, counted vmcnt(16)
// (8 gloads/wave/tile, 2 tiles in flight), SGB 1:1 interleave, branch-
// free body with clamped dead-slot prefetch.
// -------------------------------------------------------------------------
__global__ __launch_bounds__(256, 1) void gemm_i8_kernel(
    const char* __restrict__ A8,      // [M][K] int8 row-major
    const char* __restrict__ B8,      // [N][K] int8 row-major
    const float* __restrict__ scale_ptr,
    float* __restrict__ out)          // [M][N] float + 1 scalar at end
{
    extern __shared__ char lds[];     // 4 ring slots: [A 16K | B 16K] each

    const int tid  = threadIdx.x;
    const int wave = tid >> 6;        // 0..3
    const int lane = tid & 63;

    // ---- bijective XCD swizzle of the 512-block grid (512 % 8 == 0).
    int wg = (blockIdx.x & 7) * 64 + (blockIdx.x >> 3);
    const int bx = wg >> 5;           // 0..15 (N tiles)
    const int by = wg & 31;           // 0..31 (M tiles)
    const int bm = by * BM;
    const int bn = bx * BN;

    const int wm = (wave >> 1) * 128; // wave row offset in tile
    const int wn = (wave & 1) * 128;  // wave col offset in tile

    v16i acc[4][4];
#pragma unroll
    for (int mi = 0; mi < 4; ++mi)
#pragma unroll
        for (int nj = 0; nj < 4; ++nj)
#pragma unroll
            for (int r = 0; r < 16; ++r)
                acc[mi][nj][r] = 0;

    // ---- staging geometry: wave-load = 64 lanes x 16 B = 16 rows of 64 B.
    // Wave stages A rows [wave*64, +64) and B rows [wave*64, +64): 4+4
    // gloads per tile. Source granule pre-swizzled (gload_lds dest is
    // linear lane*16): f(row) = ((row>>1)&3) ^ ((row>>3)&3), row = r0+srow,
    // r0 = wave*64 + q*16 -> row bit4 = q&1.
    const int srow  = lane >> 2;                                  // 0..15
    const int fbase = ((srow >> 1) & 3) ^ ((srow >> 3) & 1);

    const char* gA[4]; const char* gB[4];
    int ldsAoff[4], ldsBoff[4];
#pragma unroll
    for (int q = 0; q < 4; ++q) {
        const int r0  = wave * 64 + q * 16;
        const int sgr = (lane & 3) ^ fbase ^ ((q & 1) << 1);
        gA[q] = A8 + (size_t)(bm + r0 + srow) * K_IN + sgr * 16;
        gB[q] = B8 + (size_t)(bn + r0 + srow) * K_IN + sgr * 16;
        ldsAoff[q] = r0 * 64;              // A at slot offset 0
        ldsBoff[q] = 16384 + r0 * 64;      // B at slot offset 16 KiB
    }

    // ISSUE_*: dest slot (tile)&3; source K clamped (dest slot is dead when
    // tile >= NT; staging stale data there is harmless; keeps body
    // branch-free and the vmcnt count uniform).
#define ISSUE_A(tile) do {                                                   \
        char* _rb = lds + ((tile) & 3) * RING_STRIDE;                        \
        const int _k0 = (((tile) < NT) ? (tile) : (NT - 1)) * BK;            \
        _Pragma("unroll")                                                    \
        for (int _q = 0; _q < 4; ++_q)                                       \
            __builtin_amdgcn_global_load_lds(                                \
                (const __attribute__((address_space(1))) void*)(gA[_q]+_k0), \
                (__attribute__((address_space(3))) void*)(_rb+ldsAoff[_q]),  \
                16, 0, 0);                                                   \
    } while (0)
#define ISSUE_B(tile) do {                                                   \
        char* _rb = lds + ((tile) & 3) * RING_STRIDE;                        \
        const int _k0 = (((tile) < NT) ? (tile) : (NT - 1)) * BK;            \
        _Pragma("unroll")                                                    \
        for (int _q = 0; _q < 4; ++_q)                                       \
            __builtin_amdgcn_global_load_lds(                                \
                (const __attribute__((address_space(1))) void*)(gB[_q]+_k0), \
                (__attribute__((address_space(3))) void*)(_rb+ldsBoff[_q]),  \
                16, 0, 0);                                                   \
    } while (0)

    // ---- fragment geometry (32x32x32 i8): lane reads 16 B of row fm at
    // global granule g = kk*2 + fh; stored LDS granule = g ^ f(row);
    // row bits 1-4 == fm bits 1-4 (bases are multiples of 32).
    const int fm  = lane & 31;
    const int fh  = lane >> 5;                          // 0/1
    const int fsw = ((fm >> 1) & 3) ^ ((fm >> 3) & 3);  // f(row)
    const int g0  = ((0 + fh) ^ fsw) << 4;              // kk=0 byte offset
    const int g1  = ((2 + fh) ^ fsw) << 4;              // kk=1 byte offset
    const int abase = (wm + fm) * 64;                   // + mi*2048
    const int bbase = 16384 + (wn + fm) * 64;           // + nj*2048

    // ---- prologue: tiles 0,1,2 in flight (24 gloads/wave)
    ISSUE_A(0); ISSUE_B(0);
    ISSUE_A(1); ISSUE_B(1);
    ISSUE_A(2); ISSUE_B(2);
    asm volatile("s_waitcnt vmcnt(16)" ::: "memory");   // tile 0 landed
    __builtin_amdgcn_s_barrier();

    // set0 <- (tile 0, phase 0)
    v4i a0[4], b0[4], a1[4], b1[4];
#pragma unroll
    for (int mi = 0; mi < 4; ++mi)
        a0[mi] = *(const v4i*)(lds + abase + mi * 2048 + g0);
#pragma unroll
    for (int nj = 0; nj < 4; ++nj)
        b0[nj] = *(const v4i*)(lds + bbase + nj * 2048 + g0);

    for (int t = 0; t < NT; ++t) {
        char* rb = lds + (t & 3) * RING_STRIDE;
        char* rn = lds + ((t + 1) & 3) * RING_STRIDE;

        // ======== phase A: reads (t,ph1)->set1, A-stage, MFMA set0 =======
#pragma unroll
        for (int mi = 0; mi < 4; ++mi)
            a1[mi] = *(const v4i*)(rb + abase + mi * 2048 + g1);
#pragma unroll
        for (int nj = 0; nj < 4; ++nj)
            b1[nj] = *(const v4i*)(rb + bbase + nj * 2048 + g1);
        ISSUE_A(t + 3);
#pragma unroll
        for (int mi = 0; mi < 4; ++mi)
#pragma unroll
            for (int nj = 0; nj < 4; ++nj)
                acc[mi][nj] = __builtin_amdgcn_mfma_i32_32x32x32_i8(
                    a0[mi], b0[nj], acc[mi][nj], 0, 0, 0);
        // interleave: each MFMA-issue stall absorbs one memory issue
        SGB(SG_DSRD, 1, 0); SGB(SG_MFMA, 1, 0);
        SGB(SG_DSRD, 1, 0); SGB(SG_MFMA, 1, 0);
        SGB(SG_DSRD, 1, 0); SGB(SG_MFMA, 1, 0);
        SGB(SG_DSRD, 1, 0); SGB(SG_MFMA, 1, 0);
        SGB(SG_DSRD, 1, 0); SGB(SG_MFMA, 1, 0);
        SGB(SG_DSRD, 1, 0); SGB(SG_MFMA, 1, 0);
        SGB(SG_DSRD, 1, 0); SGB(SG_MFMA, 1, 0);
        SGB(SG_DSRD, 1, 0); SGB(SG_MFMA, 1, 0);
        SGB(SG_VMEM, 1, 0); SGB(SG_MFMA, 1, 0);
        SGB(SG_VMEM, 1, 0); SGB(SG_MFMA, 1, 0);
        SGB(SG_VMEM, 1, 0); SGB(SG_MFMA, 1, 0);
        SGB(SG_VMEM, 1, 0); SGB(SG_MFMA, 4, 0);

        // ---- tile boundary: B-stage, counted vmcnt (never 0) + barrier.
        // Outstanding after ISSUE_B: tiles t+2 (8) + t+3 (8) = 16 ->
        // vmcnt(16) guarantees t+1 fully landed for this wave; every wave
        // does the same before the barrier.
        ISSUE_B(t + 3);
        asm volatile("s_waitcnt vmcnt(16)" ::: "memory");
        __builtin_amdgcn_s_barrier();

        // ======== phase B: reads (t+1,ph0)->set0, MFMA set1 ==============
        // (at t = NT-1 the reads hit a stale slot; values feed nothing)
#pragma unroll
        for (int mi = 0; mi < 4; ++mi)
            a0[mi] = *(const v4i*)(rn + abase + mi * 2048 + g0);
#pragma unroll
        for (int nj = 0; nj < 4; ++nj)
            b0[nj] = *(const v4i*)(rn + bbase + nj * 2048 + g0);
#pragma unroll
        for (int mi = 0; mi < 4; ++mi)
#pragma unroll
            for (int nj = 0; nj < 4; ++nj)
                acc[mi][nj] = __builtin_amdgcn_mfma_i32_32x32x32_i8(
                    a1[mi], b1[nj], acc[mi][nj], 0, 0, 0);
        SGB(SG_DSRD, 1, 0); SGB(SG_MFMA, 1, 0);
        SGB(SG_DSRD, 1, 0); SGB(SG_MFMA, 1, 0);
        SGB(SG_DSRD, 1, 0); SGB(SG_MFMA, 1, 0);
        SGB(SG_DSRD, 1, 0); SGB(SG_MFMA, 1, 0);
        SGB(SG_DSRD, 1, 0); SGB(SG_MFMA, 1, 0);
        SGB(SG_DSRD, 1, 0); SGB(SG_MFMA, 1, 0);
        SGB(SG_DSRD, 1, 0); SGB(SG_MFMA, 1, 0);
        SGB(SG_DSRD, 1, 0); SGB(SG_MFMA, 8, 0);
    }
#undef ISSUE_A
#undef ISSUE_B

    // ---- epilogue: y = clip(rint(acc * scale), -128, 127) as float
    // 32x32 C/D layout: col = lane&31, row = (reg&3) + 8*(reg>>2) + 4*(lane>>5)
    const float s     = scale_ptr[0];
    const float scale = (s * 0.1f) / 0.1f;   // match ref op order

#pragma unroll
    for (int mi = 0; mi < 4; ++mi) {
#pragma unroll
        for (int nj = 0; nj < 4; ++nj) {
#pragma unroll
            for (int r = 0; r < 16; ++r) {
                int row = bm + wm + mi * 32 + (r & 3) + 8 * (r >> 2) + 4 * fh;
                int col = bn + wn + nj * 32 + fm;
                float y = (float)acc[mi][nj][r] * scale;
                y = rintf(y);
                y = fminf(fmaxf(y, -128.0f), 127.0f);
                out[(size_t)row * N_OUT + col] = y;
            }
        }
    }

    if (bm == 0 && bn == 0 && tid == 0)
        out[(size_t)M_TOK * N_OUT] = 0.1f;
}

// -------------------------------------------------------------------------
extern "C" void kernel_launch(void* const* d_in, const int* in_sizes, int n_in,
                              void* d_out, int out_size, void* d_ws, size_t ws_size,
                              hipStream_t stream)
{
    const int*   x_q     = (const int*)d_in[0];   // [8192*4096] int32 carriers
    const int*   w_q     = (const int*)d_in[1];   // [4096*4096] int32 carriers
    const float* scale_x = (const float*)d_in[2]; // 1 element
    float* out = (float*)d_out;

    char* A8 = (char*)d_ws;                              // 32 MB
    char* B8 = (char*)d_ws + (size_t)M_TOK * K_IN;       // 16 MB

    const int n4x = (M_TOK * K_IN) / 4;   // 8388608
    const int n4w = (N_OUT * K_IN) / 4;   // 4194304

    // one-time: allow 128 KiB dynamic LDS (host-side attribute, not a
    // stream op -> graph-capture safe)
    static bool once = []{
        hipFuncSetAttribute(reinterpret_cast<const void*>(gemm_i8_kernel),
                            hipFuncAttributeMaxDynamicSharedMemorySize,
                            LDS_BYTES);
        return true;
    }();
    (void)once;

    pack_both<<<(n4x + n4w) / 256, 256, 0, stream>>>(
        (const int4*)x_q, (const int4*)w_q, (int*)A8, (int*)B8, n4x, n4w);

    // 512 blocks (16 N-tiles x 32 M-tiles), 256 threads, 128 KiB LDS
    gemm_i8_kernel<<<512, 256, LDS_BYTES, stream>>>(A8, B8, scale_x, out);
}